// Round 19
// baseline (191.802 us; speedup 1.0000x reference)
//
#include <hip/hip_runtime.h>
#include <math.h>

// Hardened single-rounded ops (never contracted/fused by the compiler):
#define FMUL(a,b) __fmul_rn((a),(b))
#define FADD(a,b) __fadd_rn((a),(b))
#define FSUB(a,b) __fsub_rn((a),(b))

#define BB 2048   // batch
#define DD 1024   // feature dim (K)
#define TT 32     // LIF steps
#define BM 32     // rows per block (4 waves x 8)
#define BN 64     // cols per block (1 col per lane)
#define KB 32     // K slab per LDS stage
#define NSLAB (DD / KB)   // 32
#define HALFS (NSLAB / 2) // chunk boundary slab (k=512)

// CONFIRMED golden semantics (r16 band 7, bit-exact; r17/r18 passed):
//   dot = FADD( fmaf-chain(k=0..511), fmaf-chain(k=512..1023) )
//   cur = FADD(dot, bias[e]); rec: m = FSUB(FADD(FMUL(0.9f,m),cur),reset)
//
// Structure: wave w owns rows r0=b0+8w..+7 (wave-uniform -> A via SCALAR loads,
// SMEM pipe, zero LDS cost); lane owns one column e. LDS serves only W
// (1 ds_read_b128 per 4k per wave). Per-element arithmetic chain unchanged.
__global__ __launch_bounds__(256) void lif_fused_kernel(
    const float* __restrict__ latent,
    const float* __restrict__ W,
    const float* __restrict__ bias,
    const float* __restrict__ gainp,
    float* __restrict__ out)
{
    __shared__ float4 Ws4[2][KB / 4][BN];   // [buf][kg][col] = 16 KB

    const int tid  = threadIdx.x;
    const int lane = tid & 63;
    const int wid  = __builtin_amdgcn_readfirstlane(tid >> 6);  // wave id 0..3

    const int e0 = blockIdx.x * BN;
    const int b0 = blockIdx.y * BM;
    const int e  = e0 + lane;          // this lane's output column
    const int r0 = b0 + wid * 8;       // this wave's first row (uniform)

    // W staging: 64 rows (output cols) x 32 k per slab; thread -> 2 float4
    const int srow = tid >> 2;         // 0..63
    const int sf   = tid & 3;          // float4 slot (and +4)
    const float* wptr = W + (size_t)(e0 + srow) * DD + sf * 4;

    // uniform A base for this wave's 8 rows -> scalar loads
    const float* __restrict__ abase = latent + (size_t)r0 * DD;

    float acc[8], tot[8];
#pragma unroll
    for (int i = 0; i < 8; ++i) { acc[i] = 0.0f; tot[i] = 0.0f; }

    // prologue: slab 0 W into regs
    float4 w0 = *(const float4*)(wptr);
    float4 w1 = *(const float4*)(wptr + 16);

    int p = 0;
    for (int s = 0; s < NSLAB; ++s) {
        Ws4[p][sf    ][srow] = w0;
        Ws4[p][sf + 4][srow] = w1;
        __syncthreads();

        if (s + 1 < NSLAB) {           // prefetch next slab into regs
            const int k0 = (s + 1) * KB;
            w0 = *(const float4*)(wptr + k0);
            w1 = *(const float4*)(wptr + k0 + 16);
        }

        if (s == HALFS) {              // chunk boundary k=512
#pragma unroll
            for (int i = 0; i < 8; ++i) { tot[i] = acc[i]; acc[i] = 0.0f; }
        }

        const float* __restrict__ aS = abase + s * KB;   // uniform pointer
#pragma unroll
        for (int kg = 0; kg < KB / 4; ++kg) {
            float4 w4 = Ws4[p][kg][lane];    // conflict-free wave b128
#pragma unroll
            for (int i = 0; i < 8; ++i) {
                const float* ai = aS + i * DD + kg * 4;  // uniform -> s_load
                float a = acc[i];
                a = fmaf(ai[0], w4.x, a);    // k ascending within group
                a = fmaf(ai[1], w4.y, a);
                a = fmaf(ai[2], w4.z, a);
                a = fmaf(ai[3], w4.w, a);
                acc[i] = a;
            }
        }
        p ^= 1;
    }

    // cur = FADD(FADD(chunk1, chunk2), bias[e])
    const float bv = bias[e];
    float cur[8], mem[8];
    int cnt[8];
#pragma unroll
    for (int i = 0; i < 8; ++i) {
        cur[i] = FADD(FADD(tot[i], acc[i]), bv);
        mem[i] = 0.0f;
        cnt[i] = 0;
    }

    // hardened f32 LIF recurrence; spike stores coalesced across lanes (e)
    float* spk = out + (size_t)BB * DD;
    for (int t = 0; t < TT; ++t) {
#pragma unroll
        for (int i = 0; i < 8; ++i) {
            float m = mem[i];
            float r = (m > 1.0f) ? 1.0f : 0.0f;
            m = FSUB(FADD(FMUL(0.9f, m), cur[i]), r);
            mem[i] = m;
            int f = (m > 1.0f) ? 1 : 0;
            cnt[i] += f;
            spk[((size_t)(r0 + i) * TT + t) * DD + e] = (float)f;
        }
    }

    // scale = 0.4*sigmoid(gain); updated = relu(latent + scale*mean_t(spikes))
    const float g = gainp[0];
    const float scale = 0.4f * (1.0f / (1.0f + expf(-g)));
#pragma unroll
    for (int i = 0; i < 8; ++i) {
        float lv = latent[(size_t)(r0 + i) * DD + e];
        float mean = (float)cnt[i] * 0.03125f;   // exact (pow2)
        float v = FADD(lv, FMUL(scale, mean));
        out[(size_t)(r0 + i) * DD + e] = v > 0.0f ? v : 0.0f;
    }

    if (blockIdx.x == 0 && blockIdx.y == 0 && tid == 0)
        out[(size_t)BB * DD + (size_t)BB * TT * DD] = scale;
}

extern "C" void kernel_launch(void* const* d_in, const int* in_sizes, int n_in,
                              void* d_out, int out_size, void* d_ws, size_t ws_size,
                              hipStream_t stream) {
    (void)in_sizes; (void)n_in; (void)d_ws; (void)ws_size; (void)out_size;
    const float* latent = (const float*)d_in[0];
    const float* W      = (const float*)d_in[1];
    const float* bias   = (const float*)d_in[2];
    const float* gain   = (const float*)d_in[3];
    float* out = (float*)d_out;

    dim3 grid(DD / BN, BB / BM);  // (16, 64) = 1024 blocks -> 4/CU
    dim3 block(256);
    lif_fused_kernel<<<grid, block, 0, stream>>>(latent, W, bias, gain, out);
}